// Round 11
// baseline (228.305 us; speedup 1.0000x reference)
//
#include <hip/hip_runtime.h>
#include <hip/hip_bf16.h>

constexpr int B_  = 128;
constexpr int N_  = 512;
constexpr int F_  = 64;
constexpr int D_  = 128;
constexpr int E_  = 8192;
constexpr int BN_ = B_ * N_;              // 65536
constexpr float SLOPE = 0.2f;
constexpr float EPS_  = 1e-5f;
constexpr int OFF_PRED = BN_ * F_;        // 4194304 (elements)
constexpr int OFF_W    = OFF_PRED + BN_;  // 4259840

// workspace float-offsets (ws = 256 MiB per the fillBuffer WRITE_SIZE)
constexpr int WS_BAR   = 16895;    // int: spin-barrier counter (zeroed by k_prep)
constexpr int WS_STATS = 16896;    // f[16][256]  bucketed (sum | sumsq), 4096 floats
constexpr int NBKT     = 16;
constexpr int WS_WLT   = 25860;    // u16[128n][64k]   (bf16 Wl^T)
constexpr int WS_WRT   = 29956;    // u16[64n][128k]   (bf16 Wr^T)

// scratch carved out of `out` (fully overwritten by phase-2 recons, which runs
// strictly after all phase-1 XT/A reads thanks to the grid-wide barrier).
// Row strides PADDED to 544 u16 (1088 B): rows shift one 64B line each, so
// 16-row gathers spread over 16 L2 channels instead of camping on 1-2.
constexpr int XTP   = 544;
constexpr int AP    = 544;
constexpr int A_U16 = B_ * F_ * XTP;      // 4,456,448

constexpr int NBLK_MEGA = 1024;           // == 256 CU x 4 blocks/CU (exact fit)

typedef __attribute__((ext_vector_type(8))) short bf16x8;
typedef __attribute__((ext_vector_type(4))) float f32x4;

__device__ __forceinline__ float lrelu(float w) { return w > 0.f ? w : SLOPE * w; }
__device__ __forceinline__ unsigned short f2b(float v) {
  __hip_bfloat16 h = __float2bfloat16(v);
  return *(unsigned short*)&h;
}
__device__ __forceinline__ float b2f(unsigned short u) {
  __hip_bfloat16 h = *(__hip_bfloat16*)&u;
  return __bfloat162float(h);
}

// K0: fused prep, grid 1856.  (round-9/10 structure + barrier-counter zero)
__global__ __launch_bounds__(256) void k_prep(
    const float* __restrict__ X, const float* __restrict__ W,
    const float* __restrict__ Wl, const float* __restrict__ Wr,
    const int* __restrict__ ei,
    float* ws, unsigned short* __restrict__ outs, float* __restrict__ out)
{
  const int t = threadIdx.x;
  const int blk = blockIdx.x;
  if (blk < 1024) {
    if (blk == 0) {
      #pragma unroll
      for (int i = 0; i < NBKT; i++) ws[WS_STATS + i * 256 + t] = 0.f;
      if (t == 0) ((int*)ws)[WS_BAR] = 0;
    }
    const int b  = blk >> 3;
    const int mh = blk & 1, fh = (blk >> 1) & 3;
    const int m  = (mh << 8) + t;
    const float* xrow = X + ((size_t)b * N_ + m) * F_ + fh * 16;
    unsigned short* xtb = outs + (size_t)b * (F_ * XTP) + fh * 16 * XTP;
    #pragma unroll
    for (int f4 = 0; f4 < 4; f4++) {
      float4 v = *(const float4*)(xrow + f4 * 4);
      xtb[(f4 * 4 + 0) * XTP + m] = f2b(v.x);
      xtb[(f4 * 4 + 1) * XTP + m] = f2b(v.y);
      xtb[(f4 * 4 + 2) * XTP + m] = f2b(v.z);
      xtb[(f4 * 4 + 3) * XTP + m] = f2b(v.w);
    }
  } else if (blk < 1056) {
    unsigned short* wlT = (unsigned short*)(ws + WS_WLT);
    int i = (blk - 1024) * 256 + t;           // [0, 8192)
    int n = i >> 6, k = i & 63;
    wlT[i] = f2b(Wl[k * D_ + n]);
  } else if (blk < 1088) {
    unsigned short* wrT = (unsigned short*)(ws + WS_WRT);
    int i = (blk - 1056) * 256 + t;           // [0, 8192)
    int n = i >> 7, k = i & 127;
    wrT[i] = f2b(Wr[k * F_ + n]);
  } else if (blk < 1344) {
    int i = (blk - 1088) * 256 + t;           // [0, 65536)
    ((float4*)(out + OFF_W))[i] = ((const float4*)W)[i];
  } else {
    // dense masked row softmax (exact duplicate handling: cnt * e^a)
    __shared__ unsigned cnt[N_];
    __shared__ float red[8];
    unsigned short* Abf = outs + A_U16;
    const int row = blk - 1344;
    const int wv = t >> 6;
    cnt[t] = 0u; cnt[t + 256] = 0u;
    __syncthreads();
    for (int e = t; e < E_; e += 256) {
      int d = ei[E_ + e];
      if (d == row) atomicAdd(&cnt[ei[e]], 1u);
    }
    __syncthreads();
    const int s0 = t, s1 = t + 256;
    const float a0 = lrelu(W[row * N_ + s0]);
    const float a1 = lrelu(W[row * N_ + s1]);
    const unsigned c0 = cnt[s0] + (s0 == row ? 1u : 0u);
    const unsigned c1 = cnt[s1] + (s1 == row ? 1u : 0u);
    float m = fmaxf(c0 ? a0 : -3.4e38f, c1 ? a1 : -3.4e38f);
    #pragma unroll
    for (int off = 32; off; off >>= 1) m = fmaxf(m, __shfl_xor(m, off));
    if ((t & 63) == 0) red[wv] = m;
    __syncthreads();
    const float amax = fmaxf(fmaxf(red[0], red[1]), fmaxf(red[2], red[3]));
    const float e0 = c0 ? (float)c0 * __expf(a0 - amax) : 0.f;
    const float e1 = c1 ? (float)c1 * __expf(a1 - amax) : 0.f;
    float sm = e0 + e1;
    #pragma unroll
    for (int off = 32; off; off >>= 1) sm += __shfl_xor(sm, off);
    if ((t & 63) == 0) red[4 + wv] = sm;
    __syncthreads();
    const float inv = 1.f / (red[4] + red[5] + red[6] + red[7]);
    Abf[row * AP + s0] = f2b(e0 * inv);
    Abf[row * AP + s1] = f2b(e1 * inv);
  }
}

// K1 (fused, grid 1024 = exactly 4 blocks/CU co-resident by capacity):
//  phase 1: Y-tile (64n x 64f) = A-slice @ XT_b (A LDS-staged) -> ys LDS
//           h-tile (64n x 128d) = Y @ Wl, kept in REGISTERS (acch)
//           BN stats -> bucketed atomics
//  spin barrier (manual count-up; all blocks resident by construction)
//  phase 2: BN params -> BN+ReLU(acch f32) -> zs LDS -> GEMM2 + pred + writes
__global__ __launch_bounds__(256, 4) void kMega(
    const float* __restrict__ gamma, const float* __restrict__ beta,
    const float* __restrict__ br, const float* __restrict__ wp,
    const float* __restrict__ bp,
    const unsigned short* __restrict__ XT, float* __restrict__ ws,
    float* __restrict__ out)
{
  constexpr int LDP = 136;     // zs row pad (breaks 256B stride)
  __shared__ __align__(16) unsigned short shm[64 * 128 + 64 * 64]; // As+ys / zs
  __shared__ float rsL[D_], zbL[D_], wpL[D_];
  unsigned short* As = shm;                 // phase 1: A K-chunk (16 KB)
  unsigned short* ys = shm + 64 * 128;      // phase 1: Y tile (8 KB)
  unsigned short* zs = shm;                 // phase 2: z tile [64][136]
  float* f = ws;
  const unsigned short* wlT = (const unsigned short*)(ws + WS_WLT);
  const unsigned short* wrT = (const unsigned short*)(ws + WS_WRT);
  const unsigned short* Abf = XT + A_U16;
  const int t = threadIdx.x;
  const int wv = t >> 6, lane = t & 63;
  const int m = lane & 15, quad = lane >> 4;
  const int b = blockIdx.x & 127, ns = blockIdx.x >> 7;   // ns in [0,8)
  const int n0 = ns * 64;

  // ---- phase 1a: Y GEMM with A LDS-staging (round-10 verified) ----
  const unsigned short* af = XT + (size_t)b * (F_ * XTP) + (wv * 16 + m) * XTP;
  const int srow = wv * 4 + (lane >> 4);    // stage: 4 rows/wave (+16p)
  const int sg   = lane & 15;               // 16B granule within 256B chunk
  f32x4 acc[4] = {{0.f,0.f,0.f,0.f},{0.f,0.f,0.f,0.f},
                  {0.f,0.f,0.f,0.f},{0.f,0.f,0.f,0.f}};
  for (int kc = 0; kc < 4; kc++) {
    #pragma unroll
    for (int p = 0; p < 4; p++) {
      const int rr = srow + 16 * p;
      bf16x8 v = *(const bf16x8*)(Abf + (n0 + rr) * AP + kc * 128 + sg * 8);
      *(bf16x8*)(As + rr * 128 + ((sg ^ (rr & 7)) << 3)) = v;
    }
    __syncthreads();
    #pragma unroll
    for (int kk = 0; kk < 4; kk++) {
      const int k0 = kc * 128 + kk * 32 + quad * 8;
      bf16x8 a = *(const bf16x8*)(af + k0);
      #pragma unroll
      for (int nt = 0; nt < 4; nt++) {
        const int n2 = nt * 16 + m;
        bf16x8 bb = *(const bf16x8*)(As + n2 * 128 +
                                     ((((kk << 2) + quad) ^ (n2 & 7)) << 3));
        acc[nt] = __builtin_amdgcn_mfma_f32_16x16x32_bf16(a, bb, acc[nt], 0, 0, 0);
      }
    }
    __syncthreads();
  }
  #pragma unroll
  for (int nt = 0; nt < 4; nt++) {          // Y tile -> swizzled ys
    const int n = nt * 16 + m;
    const int c = (wv * 16 + quad * 4) ^ ((n & 7) << 3);
    ushort4 y4;
    y4.x = f2b(acc[nt][0]); y4.y = f2b(acc[nt][1]);
    y4.z = f2b(acc[nt][2]); y4.w = f2b(acc[nt][3]);
    *(ushort4*)(ys + n * 64 + c) = y4;
  }
  __syncthreads();

  // ---- phase 1b: h GEMM (registers). wave wv owns d0 = wv*32 ----
  const int d0 = wv * 32;
  bf16x8 bw00 = *(const bf16x8*)(wlT + (d0 + m) * 64 + quad * 8);
  bf16x8 bw01 = *(const bf16x8*)(wlT + (d0 + m) * 64 + 32 + quad * 8);
  bf16x8 bw10 = *(const bf16x8*)(wlT + (d0 + 16 + m) * 64 + quad * 8);
  bf16x8 bw11 = *(const bf16x8*)(wlT + (d0 + 16 + m) * 64 + 32 + quad * 8);
  f32x4 acch[4][2];
  #pragma unroll
  for (int nt = 0; nt < 4; nt++) {
    acch[nt][0] = f32x4{0.f,0.f,0.f,0.f};
    acch[nt][1] = f32x4{0.f,0.f,0.f,0.f};
  }
  #pragma unroll
  for (int nt = 0; nt < 4; nt++) {
    const int n2 = nt * 16 + m;
    const int sw = (n2 & 7) << 3;
    bf16x8 aA = *(const bf16x8*)(ys + n2 * 64 + ((quad * 8) ^ sw));
    bf16x8 aB = *(const bf16x8*)(ys + n2 * 64 + ((32 + quad * 8) ^ sw));
    acch[nt][0] = __builtin_amdgcn_mfma_f32_16x16x32_bf16(aA, bw00, acch[nt][0], 0, 0, 0);
    acch[nt][0] = __builtin_amdgcn_mfma_f32_16x16x32_bf16(aB, bw01, acch[nt][0], 0, 0, 0);
    acch[nt][1] = __builtin_amdgcn_mfma_f32_16x16x32_bf16(aA, bw10, acch[nt][1], 0, 0, 0);
    acch[nt][1] = __builtin_amdgcn_mfma_f32_16x16x32_bf16(aB, bw11, acch[nt][1], 0, 0, 0);
  }

  // ---- phase 1c: stats -> shuffle reduce -> bucketed atomics ----
  {
    float sm0 = 0.f, sq0 = 0.f, sm1 = 0.f, sq1 = 0.f;
    #pragma unroll
    for (int nt = 0; nt < 4; nt++) {
      #pragma unroll
      for (int i = 0; i < 4; i++) {
        float v0 = acch[nt][0][i], v1 = acch[nt][1][i];
        sm0 += v0; sq0 += v0 * v0;
        sm1 += v1; sq1 += v1 * v1;
      }
    }
    sm0 += __shfl_xor(sm0, 16); sm0 += __shfl_xor(sm0, 32);
    sq0 += __shfl_xor(sq0, 16); sq0 += __shfl_xor(sq0, 32);
    sm1 += __shfl_xor(sm1, 16); sm1 += __shfl_xor(sm1, 32);
    sq1 += __shfl_xor(sq1, 16); sq1 += __shfl_xor(sq1, 32);
    if (quad == 0) {
      float* st = f + WS_STATS + (blockIdx.x & (NBKT - 1)) * 256;
      atomicAdd(&st[d0 + m], sm0);
      atomicAdd(&st[128 + d0 + m], sq0);
      atomicAdd(&st[d0 + 16 + m], sm1);
      atomicAdd(&st[128 + d0 + 16 + m], sq1);
    }
  }

  // ---- grid-wide spin barrier (all 1024 blocks co-resident by capacity) ----
  __syncthreads();            // drains this block's atomics (vmcnt(0) before s_barrier)
  {
    int* bar = (int*)ws + WS_BAR;
    if (t == 0) {
      __threadfence();
      __hip_atomic_fetch_add(bar, 1, __ATOMIC_ACQ_REL, __HIP_MEMORY_SCOPE_AGENT);
      while (__hip_atomic_load(bar, __ATOMIC_ACQUIRE, __HIP_MEMORY_SCOPE_AGENT)
             < NBLK_MEGA)
        __builtin_amdgcn_s_sleep(8);
    }
    __syncthreads();
    __threadfence();          // acquire: invalidate caches for stats reads
  }

  // ---- phase 2a: BN params (agent-scope loads) + GEMM2 B-frags ----
  if (t < 128) {
    float s = 0.f, sq = 0.f;
    #pragma unroll
    for (int bk = 0; bk < NBKT; bk++) {
      s  += __hip_atomic_load(&f[WS_STATS + bk * 256 + t],
                              __ATOMIC_RELAXED, __HIP_MEMORY_SCOPE_AGENT);
      sq += __hip_atomic_load(&f[WS_STATS + bk * 256 + 128 + t],
                              __ATOMIC_RELAXED, __HIP_MEMORY_SCOPE_AGENT);
    }
    float mu  = s * (1.f / (float)BN_);
    float var = sq * (1.f / (float)BN_) - mu * mu;
    float rg  = rsqrtf(var + EPS_) * gamma[t];
    rsL[t] = rg;
    zbL[t] = beta[t] - mu * rg;
    wpL[t] = wp[t];
  }
  const int col = wv * 16 + m;
  bf16x8 bz[4];
  #pragma unroll
  for (int s = 0; s < 4; s++)
    bz[s] = *(const bf16x8*)(wrT + col * D_ + s * 32 + quad * 8);
  const float bias = br[col];
  const float bpv = bp[0];
  __syncthreads();

  // ---- phase 2b: BN + ReLU on register h (f32) -> zs (bf16) ----
  #pragma unroll
  for (int nt = 0; nt < 4; nt++) {
    #pragma unroll
    for (int dt = 0; dt < 2; dt++) {
      const int c = d0 + dt * 16 + m;
      const float rg = rsL[c], zb = zbL[c];
      #pragma unroll
      for (int i = 0; i < 4; i++) {
        const int n = nt * 16 + quad * 4 + i;
        float z = fmaf(acch[nt][dt][i], rg, zb);
        zs[n * LDP + c] = f2b(z > 0.f ? z : 0.f);
      }
    }
  }
  __syncthreads();

  // ---- phase 2c: GEMM2 (z @ Wr), wave wv -> col-tile wv; 4 row-tiles ----
  const size_t row0g = (size_t)b * N_ + n0;
  #pragma unroll
  for (int rt = 0; rt < 4; rt++) {
    f32x4 acc2 = {bias, bias, bias, bias};
    #pragma unroll
    for (int s = 0; s < 4; s++) {
      bf16x8 az = *(const bf16x8*)(zs + (rt * 16 + m) * LDP + s * 32 + quad * 8);
      acc2 = __builtin_amdgcn_mfma_f32_16x16x32_bf16(az, bz[s], acc2, 0, 0, 0);
    }
    #pragma unroll
    for (int i = 0; i < 4; i++)
      out[(row0g + rt * 16 + quad * 4 + i) * F_ + col] = acc2[i];
  }

  // ---- phase 2d: pred head: 4 lanes per row, 32 d each ----
  {
    const int r = t >> 2, j = t & 3;
    float a = 0.f;
    #pragma unroll
    for (int k = 0; k < 32; k++) {
      const int d = j * 32 + k;
      a += b2f(zs[r * LDP + d]) * wpL[d];
    }
    a += __shfl_xor(a, 1); a += __shfl_xor(a, 2);
    if (j == 0) out[OFF_PRED + row0g + r] = a + bpv;
  }
}

extern "C" void kernel_launch(void* const* d_in, const int* in_sizes, int n_in,
                              void* d_out, int out_size, void* d_ws, size_t ws_size,
                              hipStream_t stream) {
  const float* data  = (const float*)d_in[0];
  const int*   ei    = (const int*)d_in[1];
  const float* W     = (const float*)d_in[2];
  const float* lin_w = (const float*)d_in[3];
  // d_in[4] = gnn_bias: cancels exactly through training-mode BN
  const float* gamma = (const float*)d_in[5];
  const float* beta  = (const float*)d_in[6];
  const float* Wr    = (const float*)d_in[7];
  const float* br    = (const float*)d_in[8];
  const float* wp    = (const float*)d_in[9];
  const float* bp    = (const float*)d_in[10];
  float* out = (float*)d_out;
  float* ws  = (float*)d_ws;
  unsigned short* outs = (unsigned short*)d_out;   // XT @0, A @A_U16 (scratch)

  k_prep <<<1856,      256, 0, stream>>>(data, W, lin_w, Wr, ei, ws, outs, out);
  kMega  <<<NBLK_MEGA, 256, 0, stream>>>(gamma, beta, br, wp, bp, outs, ws, out);
}

// Round 12
// 129.144 us; speedup vs baseline: 1.7678x; 1.7678x over previous
//
#include <hip/hip_runtime.h>
#include <hip/hip_bf16.h>

constexpr int B_  = 128;
constexpr int N_  = 512;
constexpr int F_  = 64;
constexpr int D_  = 128;
constexpr int E_  = 8192;
constexpr int BN_ = B_ * N_;              // 65536
constexpr float SLOPE = 0.2f;
constexpr float EPS_  = 1e-5f;
constexpr int OFF_PRED = BN_ * F_;        // 4194304 (elements)
constexpr int OFF_W    = OFF_PRED + BN_;  // 4259840

// workspace float-offsets (ws = 256 MiB per the fillBuffer WRITE_SIZE)
constexpr int WS_STATS = 16896;    // f[16][256]  bucketed (sum | sumsq), 4096 floats
constexpr int NBKT     = 16;
constexpr int WS_WLT   = 25860;    // u16[128n][64k]   (bf16 Wl^T)
constexpr int WS_WRT   = 29956;    // u16[64n][128k]   (bf16 Wr^T)
constexpr int WS_H     = 34052;    // Hf bf16, 16.7MB (byte 136208, 16B aligned)
// H is stored in MFMA A-FRAGMENT layout: Hf[rblk][s][lane][8] u16 where
// rblk = row>>4, s = col>>5, lane = ((col>>3)&3)*16 + (row&15), j = col&7.
// kD's per-(rt,s) load is then 64 lanes x 16B CONSECUTIVE (1KB streaming).

// scratch carved out of `out` (fully overwritten later by kD's recons).
// Row strides PADDED to 544 u16 (1088 B): rows shift one 64B line each, so
// 16-row gathers spread over 16 L2 channels instead of camping on 1-2.
constexpr int XTP   = 544;
constexpr int AP    = 544;
constexpr int A_U16 = B_ * F_ * XTP;      // 4,456,448

typedef __attribute__((ext_vector_type(8))) short bf16x8;
typedef __attribute__((ext_vector_type(4))) float f32x4;

__device__ __forceinline__ float lrelu(float w) { return w > 0.f ? w : SLOPE * w; }
__device__ __forceinline__ unsigned short f2b(float v) {
  __hip_bfloat16 h = __float2bfloat16(v);
  return *(unsigned short*)&h;
}
__device__ __forceinline__ float b2f(unsigned short u) {
  __hip_bfloat16 h = *(__hip_bfloat16*)&u;
  return __bfloat162float(h);
}

// K0: fused prep, grid 1856.  (unchanged from round 10)
__global__ __launch_bounds__(256) void k_prep(
    const float* __restrict__ X, const float* __restrict__ W,
    const float* __restrict__ Wl, const float* __restrict__ Wr,
    const int* __restrict__ ei,
    float* ws, unsigned short* __restrict__ outs, float* __restrict__ out)
{
  const int t = threadIdx.x;
  const int blk = blockIdx.x;
  if (blk < 1024) {
    if (blk == 0) {
      #pragma unroll
      for (int i = 0; i < NBKT; i++) ws[WS_STATS + i * 256 + t] = 0.f;
    }
    const int b  = blk >> 3;
    const int mh = blk & 1, fh = (blk >> 1) & 3;
    const int m  = (mh << 8) + t;
    const float* xrow = X + ((size_t)b * N_ + m) * F_ + fh * 16;
    unsigned short* xtb = outs + (size_t)b * (F_ * XTP) + fh * 16 * XTP;
    #pragma unroll
    for (int f4 = 0; f4 < 4; f4++) {
      float4 v = *(const float4*)(xrow + f4 * 4);
      xtb[(f4 * 4 + 0) * XTP + m] = f2b(v.x);
      xtb[(f4 * 4 + 1) * XTP + m] = f2b(v.y);
      xtb[(f4 * 4 + 2) * XTP + m] = f2b(v.z);
      xtb[(f4 * 4 + 3) * XTP + m] = f2b(v.w);
    }
  } else if (blk < 1056) {
    unsigned short* wlT = (unsigned short*)(ws + WS_WLT);
    int i = (blk - 1024) * 256 + t;           // [0, 8192)
    int n = i >> 6, k = i & 63;
    wlT[i] = f2b(Wl[k * D_ + n]);
  } else if (blk < 1088) {
    unsigned short* wrT = (unsigned short*)(ws + WS_WRT);
    int i = (blk - 1056) * 256 + t;           // [0, 8192)
    int n = i >> 7, k = i & 127;
    wrT[i] = f2b(Wr[k * F_ + n]);
  } else if (blk < 1344) {
    int i = (blk - 1088) * 256 + t;           // [0, 65536)
    ((float4*)(out + OFF_W))[i] = ((const float4*)W)[i];
  } else {
    // dense masked row softmax (exact duplicate handling: cnt * e^a)
    __shared__ unsigned cnt[N_];
    __shared__ float red[8];
    unsigned short* Abf = outs + A_U16;
    const int row = blk - 1344;
    const int wv = t >> 6;
    cnt[t] = 0u; cnt[t + 256] = 0u;
    __syncthreads();
    for (int e = t; e < E_; e += 256) {
      int d = ei[E_ + e];
      if (d == row) atomicAdd(&cnt[ei[e]], 1u);
    }
    __syncthreads();
    const int s0 = t, s1 = t + 256;
    const float a0 = lrelu(W[row * N_ + s0]);
    const float a1 = lrelu(W[row * N_ + s1]);
    const unsigned c0 = cnt[s0] + (s0 == row ? 1u : 0u);
    const unsigned c1 = cnt[s1] + (s1 == row ? 1u : 0u);
    float m = fmaxf(c0 ? a0 : -3.4e38f, c1 ? a1 : -3.4e38f);
    #pragma unroll
    for (int off = 32; off; off >>= 1) m = fmaxf(m, __shfl_xor(m, off));
    if ((t & 63) == 0) red[wv] = m;
    __syncthreads();
    const float amax = fmaxf(fmaxf(red[0], red[1]), fmaxf(red[2], red[3]));
    const float e0 = c0 ? (float)c0 * __expf(a0 - amax) : 0.f;
    const float e1 = c1 ? (float)c1 * __expf(a1 - amax) : 0.f;
    float sm = e0 + e1;
    #pragma unroll
    for (int off = 32; off; off >>= 1) sm += __shfl_xor(sm, off);
    if ((t & 63) == 0) red[4 + wv] = sm;
    __syncthreads();
    const float inv = 1.f / (red[4] + red[5] + red[6] + red[7]);
    Abf[row * AP + s0] = f2b(e0 * inv);
    Abf[row * AP + s1] = f2b(e1 * inv);
  }
}

// K1: aggregation + projection + BN stats; A LDS-staged WITH register
// prefetch pipeline (T14): next chunk's A-stage + XT a-frag loads are issued
// right after the barrier, so their latency hides under this chunk's MFMAs.
// grid = 1024: b = blk&127 (blocks sharing XT_b sit stride-128 => same XCD).
__global__ __launch_bounds__(256, 4) void kBC(
    const unsigned short* __restrict__ XT, float* ws)
{
  __shared__ __align__(16) unsigned short As[64 * 128];   // A K-chunk, swizzled
  __shared__ __align__(16) unsigned short ys[64 * 64];    // Y tile, XOR-swizzled
  float* f = ws;
  unsigned short* H = (unsigned short*)(ws + WS_H);
  const unsigned short* wlT = (const unsigned short*)(ws + WS_WLT);
  const unsigned short* Abf = XT + A_U16;
  const int t = threadIdx.x;
  const int wv = t >> 6, lane = t & 63;
  const int m = lane & 15, quad = lane >> 4;
  const int b = blockIdx.x & 127, ns = blockIdx.x >> 7;   // ns in [0,8)
  const int n0 = ns * 64;

  // ---- Y GEMM: Y^T[f][n] = XT_b[f][:] . A[n][:]; wave wv = f-rows [16wv,16wv+16) ----
  const unsigned short* af = XT + (size_t)b * (F_ * XTP) + (wv * 16 + m) * XTP;
  const int srow = wv * 4 + (lane >> 4);    // stage: 4 rows/wave (+16p)
  const int sg   = lane & 15;               // 16B granule within 256B chunk
  f32x4 acc[4] = {{0.f,0.f,0.f,0.f},{0.f,0.f,0.f,0.f},
                  {0.f,0.f,0.f,0.f},{0.f,0.f,0.f,0.f}};
  bf16x8 vreg[4], areg[4], aregN[4];
  // prologue: chunk-0 loads into registers
  #pragma unroll
  for (int p = 0; p < 4; p++) {
    const int rr = srow + 16 * p;
    vreg[p] = *(const bf16x8*)(Abf + (n0 + rr) * AP + sg * 8);
  }
  #pragma unroll
  for (int kk = 0; kk < 4; kk++)
    areg[kk] = *(const bf16x8*)(af + kk * 32 + quad * 8);

  for (int kc = 0; kc < 4; kc++) {
    // write staged A regs -> swizzled LDS
    #pragma unroll
    for (int p = 0; p < 4; p++) {
      const int rr = srow + 16 * p;
      *(bf16x8*)(As + rr * 128 + ((sg ^ (rr & 7)) << 3)) = vreg[p];
    }
    __syncthreads();
    // issue NEXT chunk's loads now (latency hides under MFMAs below)
    if (kc < 3) {
      #pragma unroll
      for (int p = 0; p < 4; p++) {
        const int rr = srow + 16 * p;
        vreg[p] = *(const bf16x8*)(Abf + (n0 + rr) * AP + (kc + 1) * 128 + sg * 8);
      }
      #pragma unroll
      for (int kk = 0; kk < 4; kk++)
        aregN[kk] = *(const bf16x8*)(af + (kc + 1) * 128 + kk * 32 + quad * 8);
    }
    // MFMAs over this chunk (a from regs, bb from conflict-free LDS)
    #pragma unroll
    for (int kk = 0; kk < 4; kk++) {
      bf16x8 a = areg[kk];
      #pragma unroll
      for (int nt = 0; nt < 4; nt++) {
        const int n2 = nt * 16 + m;
        bf16x8 bb = *(const bf16x8*)(As + n2 * 128 +
                                     ((((kk << 2) + quad) ^ (n2 & 7)) << 3));
        acc[nt] = __builtin_amdgcn_mfma_f32_16x16x32_bf16(a, bb, acc[nt], 0, 0, 0);
      }
    }
    __syncthreads();
    #pragma unroll
    for (int kk = 0; kk < 4; kk++) areg[kk] = aregN[kk];
  }
  // Y tile -> swizzled ys
  #pragma unroll
  for (int nt = 0; nt < 4; nt++) {
    const int n = nt * 16 + m;
    const int c = (wv * 16 + quad * 4) ^ ((n & 7) << 3);
    ushort4 y4;
    y4.x = f2b(acc[nt][0]); y4.y = f2b(acc[nt][1]);
    y4.z = f2b(acc[nt][2]); y4.w = f2b(acc[nt][3]);
    *(ushort4*)(ys + n * 64 + c) = y4;
  }
  __syncthreads();

  // ---- h GEMM: wave wv owns d0 = wv*32 ----
  const int d0 = wv * 32;
  bf16x8 bw00 = *(const bf16x8*)(wlT + (d0 + m) * 64 + quad * 8);
  bf16x8 bw01 = *(const bf16x8*)(wlT + (d0 + m) * 64 + 32 + quad * 8);
  bf16x8 bw10 = *(const bf16x8*)(wlT + (d0 + 16 + m) * 64 + quad * 8);
  bf16x8 bw11 = *(const bf16x8*)(wlT + (d0 + 16 + m) * 64 + 32 + quad * 8);
  f32x4 acch[4][2];
  #pragma unroll
  for (int nt = 0; nt < 4; nt++) {
    acch[nt][0] = f32x4{0.f,0.f,0.f,0.f};
    acch[nt][1] = f32x4{0.f,0.f,0.f,0.f};
  }
  #pragma unroll
  for (int nt = 0; nt < 4; nt++) {
    const int n2 = nt * 16 + m;
    const int sw = (n2 & 7) << 3;
    bf16x8 aA = *(const bf16x8*)(ys + n2 * 64 + ((quad * 8) ^ sw));
    bf16x8 aB = *(const bf16x8*)(ys + n2 * 64 + ((32 + quad * 8) ^ sw));
    acch[nt][0] = __builtin_amdgcn_mfma_f32_16x16x32_bf16(aA, bw00, acch[nt][0], 0, 0, 0);
    acch[nt][0] = __builtin_amdgcn_mfma_f32_16x16x32_bf16(aB, bw01, acch[nt][0], 0, 0, 0);
    acch[nt][1] = __builtin_amdgcn_mfma_f32_16x16x32_bf16(aA, bw10, acch[nt][1], 0, 0, 0);
    acch[nt][1] = __builtin_amdgcn_mfma_f32_16x16x32_bf16(aB, bw11, acch[nt][1], 0, 0, 0);
  }

  // ---- Hf store (fragment layout) + stat accumulation ----
  const int lhi = m >> 3, jlo = m & 7;
  float sm0 = 0.f, sq0 = 0.f, sm1 = 0.f, sq1 = 0.f;
  #pragma unroll
  for (int nt = 0; nt < 4; nt++) {
    unsigned short* hb = H + ((size_t)((b * 32 + ns * 4 + nt) * 4 + wv)) * 512;
    #pragma unroll
    for (int i = 0; i < 4; i++) {
      float v0 = acch[nt][0][i], v1 = acch[nt][1][i];
      sm0 += v0; sq0 += v0 * v0;
      sm1 += v1; sq1 += v1 * v1;
      hb[((0 + lhi) * 16 + quad * 4 + i) * 8 + jlo] = f2b(v0);
      hb[((2 + lhi) * 16 + quad * 4 + i) * 8 + jlo] = f2b(v1);
    }
  }
  sm0 += __shfl_xor(sm0, 16); sm0 += __shfl_xor(sm0, 32);
  sq0 += __shfl_xor(sq0, 16); sq0 += __shfl_xor(sq0, 32);
  sm1 += __shfl_xor(sm1, 16); sm1 += __shfl_xor(sm1, 32);
  sq1 += __shfl_xor(sq1, 16); sq1 += __shfl_xor(sq1, 32);
  if (quad == 0) {
    float* st = f + WS_STATS + (blockIdx.x & (NBKT - 1)) * 256;
    atomicAdd(&st[d0 + m], sm0);
    atomicAdd(&st[128 + d0 + m], sq0);
    atomicAdd(&st[d0 + 16 + m], sm1);
    atomicAdd(&st[128 + d0 + 16 + m], sq1);
  }
}

// K2: epilogue, register-resident: Hf frag reads (1KB streaming per instr),
// BN+ReLU in-reg, GEMM2 + pred. grid 1024 (4 blocks/CU), 64 rows/block.
__global__ __launch_bounds__(256, 4) void kD(
    const float* __restrict__ gamma, const float* __restrict__ beta,
    const float* __restrict__ br, const float* __restrict__ wp,
    const float* __restrict__ bp, float* ws, float* __restrict__ out)
{
  __shared__ float rsL[D_], zbL[D_], wpL[D_];
  float* f = ws;
  const unsigned short* H   = (const unsigned short*)(f + WS_H);
  const unsigned short* wrT = (const unsigned short*)(f + WS_WRT);
  const int t = threadIdx.x;
  const int wv = t >> 6, lane = t & 63;
  const int m = lane & 15, quad = lane >> 4;
  const size_t row0 = (size_t)blockIdx.x * 64;
  const size_t rblk0 = (size_t)blockIdx.x * 4;

  if (t < 128) {
    float s = 0.f, sq = 0.f;
    #pragma unroll
    for (int bk = 0; bk < NBKT; bk++) {
      s  += f[WS_STATS + bk * 256 + t];
      sq += f[WS_STATS + bk * 256 + 128 + t];
    }
    float mu  = s * (1.f / (float)BN_);
    float var = sq * (1.f / (float)BN_) - mu * mu;
    float rg  = rsqrtf(var + EPS_) * gamma[t];
    rsL[t] = rg;
    zbL[t] = beta[t] - mu * rg;
    wpL[t] = wp[t];
  }
  // B-frags for GEMM2 (col = wv*16+m, fixed per lane), loaded once
  const int col = wv * 16 + m;
  bf16x8 bz[4];
  #pragma unroll
  for (int s = 0; s < 4; s++)
    bz[s] = *(const bf16x8*)(wrT + col * D_ + s * 32 + quad * 8);
  const float bias = br[col];
  const float bpv = bp[0];
  __syncthreads();

  #pragma unroll
  for (int rt = 0; rt < 4; rt++) {
    const size_t row = row0 + rt * 16 + m;      // this lane's logical H row
    float predp = 0.f;
    f32x4 acc2 = {bias, bias, bias, bias};
    #pragma unroll
    for (int s = 0; s < 4; s++) {
      const int cbase = s * 32 + quad * 8;
      // Hf: wave reads lanes 0..63 consecutive -> 1KB contiguous
      bf16x8 h8 = *(const bf16x8*)(H + (((rblk0 + rt) * 4 + s) * 64 + lane) * 8);
      bf16x8 z8;
      #pragma unroll
      for (int j = 0; j < 8; j++) {
        const int c = cbase + j;
        float z = fmaf(b2f((unsigned short)h8[j]), rsL[c], zbL[c]);
        z = z > 0.f ? z : 0.f;
        predp += z * wpL[c];
        z8[j] = (short)f2b(z);
      }
      acc2 = __builtin_amdgcn_mfma_f32_16x16x32_bf16(z8, bz[s], acc2, 0, 0, 0);
    }
    // pred: combine the 4 quads holding row's 128 cols
    predp += __shfl_xor(predp, 16); predp += __shfl_xor(predp, 32);
    if (quad == 0) out[OFF_PRED + row] = predp + bpv;
    // recons: C-layout rows quad*4+i, col = wv*16+m
    #pragma unroll
    for (int i = 0; i < 4; i++)
      out[(row0 + rt * 16 + quad * 4 + i) * F_ + col] = acc2[i];
  }
}

extern "C" void kernel_launch(void* const* d_in, const int* in_sizes, int n_in,
                              void* d_out, int out_size, void* d_ws, size_t ws_size,
                              hipStream_t stream) {
  const float* data  = (const float*)d_in[0];
  const int*   ei    = (const int*)d_in[1];
  const float* W     = (const float*)d_in[2];
  const float* lin_w = (const float*)d_in[3];
  // d_in[4] = gnn_bias: cancels exactly through training-mode BN
  const float* gamma = (const float*)d_in[5];
  const float* beta  = (const float*)d_in[6];
  const float* Wr    = (const float*)d_in[7];
  const float* br    = (const float*)d_in[8];
  const float* wp    = (const float*)d_in[9];
  const float* bp    = (const float*)d_in[10];
  float* out = (float*)d_out;
  float* ws  = (float*)d_ws;
  unsigned short* outs = (unsigned short*)d_out;   // XT @0, A @A_U16 (scratch)

  k_prep <<<1856, 256, 0, stream>>>(data, W, lin_w, Wr, ei, ws, outs, out);
  kBC    <<<1024, 256, 0, stream>>>(outs, ws);
  kD     <<<1024, 256, 0, stream>>>(gamma, beta, br, wp, bp, ws, out);
}

// Round 14
// 124.564 us; speedup vs baseline: 1.8328x; 1.0368x over previous
//
#include <hip/hip_runtime.h>
#include <hip/hip_bf16.h>

constexpr int B_  = 128;
constexpr int N_  = 512;
constexpr int F_  = 64;
constexpr int D_  = 128;
constexpr int E_  = 8192;
constexpr int BN_ = B_ * N_;              // 65536
constexpr float SLOPE = 0.2f;
constexpr float EPS_  = 1e-5f;
constexpr int OFF_PRED = BN_ * F_;        // 4194304 (elements)
constexpr int OFF_W    = OFF_PRED + BN_;  // 4259840

// workspace float-offsets (ws = 256 MiB per the fillBuffer WRITE_SIZE)
constexpr int WS_STATS = 16896;    // f[16][256]  bucketed (sum | sumsq), 4096 floats
constexpr int NBKT     = 16;
constexpr int WS_WLT   = 25860;    // u16[128n][64k]   (bf16 Wl^T)
constexpr int WS_WRT   = 29956;    // u16[64n][128k]   (bf16 Wr^T)
constexpr int WS_H     = 34052;    // Hf bf16, 16.7MB (byte 136208, 16B aligned)
// H is stored in MFMA A-FRAGMENT layout: Hf[rblk][s][lane][8] u16 where
// rblk = row>>4, s = col>>5, lane = ((col>>3)&3)*16 + (row&15), j = col&7.
// kD's per-(rt,s) load is then 64 lanes x 16B CONSECUTIVE (1KB streaming).

// scratch carved out of `out` (fully overwritten later by kD's recons).
// Row strides PADDED to 544 u16 (1088 B): rows shift one 64B line each, so
// 16-row gathers spread over 16 L2 channels instead of camping on 1-2.
constexpr int XTP   = 544;
constexpr int AP    = 544;
constexpr int A_U16 = B_ * F_ * XTP;      // 4,456,448

typedef __attribute__((ext_vector_type(8))) short bf16x8;
typedef __attribute__((ext_vector_type(4))) float f32x4;

__device__ __forceinline__ float lrelu(float w) { return w > 0.f ? w : SLOPE * w; }
__device__ __forceinline__ unsigned short f2b(float v) {
  __hip_bfloat16 h = __float2bfloat16(v);
  return *(unsigned short*)&h;
}
__device__ __forceinline__ float b2f(unsigned short u) {
  __hip_bfloat16 h = *(__hip_bfloat16*)&u;
  return __bfloat162float(h);
}

// K0: fused prep, grid 1856.
//   [   0,1024): X -> XT via LDS tile transpose (coalesced both sides)
//                (1024 = 128 b x 8 msegs; each block owns a [64m x 64f] tile)
//   [1024,1056): wlT[n][k] = bf16(Wl[k][n])   (block 1024 zeros stat buckets)
//   [1056,1088): wrT[n][k] = bf16(Wr[k][n])
//   [1088,1344): W passthrough copy (float4)
//   [1344,1856): dense softmax row build (one block per dst node)
__global__ __launch_bounds__(256) void k_prep(
    const float* __restrict__ X, const float* __restrict__ W,
    const float* __restrict__ Wl, const float* __restrict__ Wr,
    const int* __restrict__ ei,
    float* ws, unsigned short* __restrict__ outs, float* __restrict__ out)
{
  const int t = threadIdx.x;
  const int blk = blockIdx.x;
  if (blk < 1024) {
    // [64 m x 64 f] tile transpose through LDS.
    // Phase 1: linear float4 reads of X (fully coalesced: wave = 1KB run),
    //          bf16 scatter into xs[f][m], stride 66 u16 (~2-way conflicts).
    // Phase 2: dword reads of xs rows, uint4 writes to XT (32B/thread).
    __shared__ unsigned short xs[64 * 66];
    const int b = blk >> 3, mseg = blk & 7;   // b in [0,128), mseg in [0,8)
    const float4* src = (const float4*)(X + ((size_t)b * N_ + mseg * 64) * F_);
    #pragma unroll
    for (int p = 0; p < 4; p++) {
      const int idx = p * 256 + t;          // [0, 1024) float4s
      float4 v = src[idx];
      const int ml = idx >> 4;              // m_local 0..63
      const int f0 = (idx & 15) << 2;       // f 0..63 step 4
      xs[(f0 + 0) * 66 + ml] = f2b(v.x);
      xs[(f0 + 1) * 66 + ml] = f2b(v.y);
      xs[(f0 + 2) * 66 + ml] = f2b(v.z);
      xs[(f0 + 3) * 66 + ml] = f2b(v.w);
    }
    __syncthreads();
    const int fr = t >> 2, j8 = t & 3;      // f-row, 16-m chunk
    const char* r = (const char*)(xs + fr * 66 + j8 * 16);  // 4B aligned
    unsigned u[8];
    #pragma unroll
    for (int c = 0; c < 8; c++) u[c] = *(const unsigned*)(r + 4 * c);
    unsigned short* dst = outs + (size_t)b * (F_ * XTP) + fr * XTP
                               + mseg * 64 + j8 * 16;        // 16B aligned
    *(uint4*)(dst)     = make_uint4(u[0], u[1], u[2], u[3]);
    *(uint4*)(dst + 8) = make_uint4(u[4], u[5], u[6], u[7]);
  } else if (blk < 1056) {
    if (blk == 1024) {
      #pragma unroll
      for (int i = 0; i < NBKT; i++) ws[WS_STATS + i * 256 + t] = 0.f;
    }
    unsigned short* wlT = (unsigned short*)(ws + WS_WLT);
    int i = (blk - 1024) * 256 + t;           // [0, 8192)
    int n = i >> 6, k = i & 63;
    wlT[i] = f2b(Wl[k * D_ + n]);
  } else if (blk < 1088) {
    unsigned short* wrT = (unsigned short*)(ws + WS_WRT);
    int i = (blk - 1056) * 256 + t;           // [0, 8192)
    int n = i >> 7, k = i & 127;
    wrT[i] = f2b(Wr[k * F_ + n]);
  } else if (blk < 1344) {
    int i = (blk - 1088) * 256 + t;           // [0, 65536)
    ((float4*)(out + OFF_W))[i] = ((const float4*)W)[i];
  } else {
    // dense masked row softmax (exact duplicate handling: cnt * e^a)
    __shared__ unsigned cnt[N_];
    __shared__ float red[8];
    unsigned short* Abf = outs + A_U16;
    const int row = blk - 1344;
    const int wv = t >> 6;
    cnt[t] = 0u; cnt[t + 256] = 0u;
    __syncthreads();
    for (int e = t; e < E_; e += 256) {
      int d = ei[E_ + e];
      if (d == row) atomicAdd(&cnt[ei[e]], 1u);
    }
    __syncthreads();
    const int s0 = t, s1 = t + 256;
    const float a0 = lrelu(W[row * N_ + s0]);
    const float a1 = lrelu(W[row * N_ + s1]);
    const unsigned c0 = cnt[s0] + (s0 == row ? 1u : 0u);
    const unsigned c1 = cnt[s1] + (s1 == row ? 1u : 0u);
    float m = fmaxf(c0 ? a0 : -3.4e38f, c1 ? a1 : -3.4e38f);
    #pragma unroll
    for (int off = 32; off; off >>= 1) m = fmaxf(m, __shfl_xor(m, off));
    if ((t & 63) == 0) red[wv] = m;
    __syncthreads();
    const float amax = fmaxf(fmaxf(red[0], red[1]), fmaxf(red[2], red[3]));
    const float e0 = c0 ? (float)c0 * __expf(a0 - amax) : 0.f;
    const float e1 = c1 ? (float)c1 * __expf(a1 - amax) : 0.f;
    float sm = e0 + e1;
    #pragma unroll
    for (int off = 32; off; off >>= 1) sm += __shfl_xor(sm, off);
    if ((t & 63) == 0) red[4 + wv] = sm;
    __syncthreads();
    const float inv = 1.f / (red[4] + red[5] + red[6] + red[7]);
    Abf[row * AP + s0] = f2b(e0 * inv);
    Abf[row * AP + s1] = f2b(e1 * inv);
  }
}

// K1: aggregation + projection + BN stats; A LDS-staged WITH register
// prefetch pipeline; writes Hf fragment layout.  (unchanged from round 12)
// grid = 1024: b = blk&127 (blocks sharing XT_b sit stride-128 => same XCD).
__global__ __launch_bounds__(256, 4) void kBC(
    const unsigned short* __restrict__ XT, float* ws)
{
  __shared__ __align__(16) unsigned short As[64 * 128];   // A K-chunk, swizzled
  __shared__ __align__(16) unsigned short ys[64 * 64];    // Y tile, XOR-swizzled
  float* f = ws;
  unsigned short* H = (unsigned short*)(ws + WS_H);
  const unsigned short* wlT = (const unsigned short*)(ws + WS_WLT);
  const unsigned short* Abf = XT + A_U16;
  const int t = threadIdx.x;
  const int wv = t >> 6, lane = t & 63;
  const int m = lane & 15, quad = lane >> 4;
  const int b = blockIdx.x & 127, ns = blockIdx.x >> 7;   // ns in [0,8)
  const int n0 = ns * 64;

  // ---- Y GEMM: Y^T[f][n] = XT_b[f][:] . A[n][:]; wave wv = f-rows [16wv,16wv+16) ----
  const unsigned short* af = XT + (size_t)b * (F_ * XTP) + (wv * 16 + m) * XTP;
  const int srow = wv * 4 + (lane >> 4);    // stage: 4 rows/wave (+16p)
  const int sg   = lane & 15;               // 16B granule within 256B chunk
  f32x4 acc[4] = {{0.f,0.f,0.f,0.f},{0.f,0.f,0.f,0.f},
                  {0.f,0.f,0.f,0.f},{0.f,0.f,0.f,0.f}};
  bf16x8 vreg[4], areg[4], aregN[4];
  #pragma unroll
  for (int p = 0; p < 4; p++) {
    const int rr = srow + 16 * p;
    vreg[p] = *(const bf16x8*)(Abf + (n0 + rr) * AP + sg * 8);
  }
  #pragma unroll
  for (int kk = 0; kk < 4; kk++)
    areg[kk] = *(const bf16x8*)(af + kk * 32 + quad * 8);

  for (int kc = 0; kc < 4; kc++) {
    #pragma unroll
    for (int p = 0; p < 4; p++) {
      const int rr = srow + 16 * p;
      *(bf16x8*)(As + rr * 128 + ((sg ^ (rr & 7)) << 3)) = vreg[p];
    }
    __syncthreads();
    if (kc < 3) {
      #pragma unroll
      for (int p = 0; p < 4; p++) {
        const int rr = srow + 16 * p;
        vreg[p] = *(const bf16x8*)(Abf + (n0 + rr) * AP + (kc + 1) * 128 + sg * 8);
      }
      #pragma unroll
      for (int kk = 0; kk < 4; kk++)
        aregN[kk] = *(const bf16x8*)(af + (kc + 1) * 128 + kk * 32 + quad * 8);
    }
    #pragma unroll
    for (int kk = 0; kk < 4; kk++) {
      bf16x8 a = areg[kk];
      #pragma unroll
      for (int nt = 0; nt < 4; nt++) {
        const int n2 = nt * 16 + m;
        bf16x8 bb = *(const bf16x8*)(As + n2 * 128 +
                                     ((((kk << 2) + quad) ^ (n2 & 7)) << 3));
        acc[nt] = __builtin_amdgcn_mfma_f32_16x16x32_bf16(a, bb, acc[nt], 0, 0, 0);
      }
    }
    __syncthreads();
    #pragma unroll
    for (int kk = 0; kk < 4; kk++) areg[kk] = aregN[kk];
  }
  #pragma unroll
  for (int nt = 0; nt < 4; nt++) {
    const int n = nt * 16 + m;
    const int c = (wv * 16 + quad * 4) ^ ((n & 7) << 3);
    ushort4 y4;
    y4.x = f2b(acc[nt][0]); y4.y = f2b(acc[nt][1]);
    y4.z = f2b(acc[nt][2]); y4.w = f2b(acc[nt][3]);
    *(ushort4*)(ys + n * 64 + c) = y4;
  }
  __syncthreads();

  // ---- h GEMM: wave wv owns d0 = wv*32 ----
  const int d0 = wv * 32;
  bf16x8 bw00 = *(const bf16x8*)(wlT + (d0 + m) * 64 + quad * 8);
  bf16x8 bw01 = *(const bf16x8*)(wlT + (d0 + m) * 64 + 32 + quad * 8);
  bf16x8 bw10 = *(const bf16x8*)(wlT + (d0 + 16 + m) * 64 + quad * 8);
  bf16x8 bw11 = *(const bf16x8*)(wlT + (d0 + 16 + m) * 64 + 32 + quad * 8);
  f32x4 acch[4][2];
  #pragma unroll
  for (int nt = 0; nt < 4; nt++) {
    acch[nt][0] = f32x4{0.f,0.f,0.f,0.f};
    acch[nt][1] = f32x4{0.f,0.f,0.f,0.f};
  }
  #pragma unroll
  for (int nt = 0; nt < 4; nt++) {
    const int n2 = nt * 16 + m;
    const int sw = (n2 & 7) << 3;
    bf16x8 aA = *(const bf16x8*)(ys + n2 * 64 + ((quad * 8) ^ sw));
    bf16x8 aB = *(const bf16x8*)(ys + n2 * 64 + ((32 + quad * 8) ^ sw));
    acch[nt][0] = __builtin_amdgcn_mfma_f32_16x16x32_bf16(aA, bw00, acch[nt][0], 0, 0, 0);
    acch[nt][0] = __builtin_amdgcn_mfma_f32_16x16x32_bf16(aB, bw01, acch[nt][0], 0, 0, 0);
    acch[nt][1] = __builtin_amdgcn_mfma_f32_16x16x32_bf16(aA, bw10, acch[nt][1], 0, 0, 0);
    acch[nt][1] = __builtin_amdgcn_mfma_f32_16x16x32_bf16(aB, bw11, acch[nt][1], 0, 0, 0);
  }

  // ---- Hf store (fragment layout) + stat accumulation ----
  const int lhi = m >> 3, jlo = m & 7;
  float sm0 = 0.f, sq0 = 0.f, sm1 = 0.f, sq1 = 0.f;
  #pragma unroll
  for (int nt = 0; nt < 4; nt++) {
    unsigned short* hb = H + ((size_t)((b * 32 + ns * 4 + nt) * 4 + wv)) * 512;
    #pragma unroll
    for (int i = 0; i < 4; i++) {
      float v0 = acch[nt][0][i], v1 = acch[nt][1][i];
      sm0 += v0; sq0 += v0 * v0;
      sm1 += v1; sq1 += v1 * v1;
      hb[((0 + lhi) * 16 + quad * 4 + i) * 8 + jlo] = f2b(v0);
      hb[((2 + lhi) * 16 + quad * 4 + i) * 8 + jlo] = f2b(v1);
    }
  }
  sm0 += __shfl_xor(sm0, 16); sm0 += __shfl_xor(sm0, 32);
  sq0 += __shfl_xor(sq0, 16); sq0 += __shfl_xor(sq0, 32);
  sm1 += __shfl_xor(sm1, 16); sm1 += __shfl_xor(sm1, 32);
  sq1 += __shfl_xor(sq1, 16); sq1 += __shfl_xor(sq1, 32);
  if (quad == 0) {
    float* st = f + WS_STATS + (blockIdx.x & (NBKT - 1)) * 256;
    atomicAdd(&st[d0 + m], sm0);
    atomicAdd(&st[128 + d0 + m], sq0);
    atomicAdd(&st[d0 + 16 + m], sm1);
    atomicAdd(&st[128 + d0 + 16 + m], sq1);
  }
}

// K2: epilogue, register-resident: Hf frag reads (1KB streaming per instr),
// BN+ReLU in-reg, GEMM2 + pred. grid 1024 (4 blocks/CU), 64 rows/block.
__global__ __launch_bounds__(256, 4) void kD(
    const float* __restrict__ gamma, const float* __restrict__ beta,
    const float* __restrict__ br, const float* __restrict__ wp,
    const float* __restrict__ bp, float* ws, float* __restrict__ out)
{
  __shared__ float rsL[D_], zbL[D_], wpL[D_];
  float* f = ws;
  const unsigned short* H   = (const unsigned short*)(f + WS_H);
  const unsigned short* wrT = (const unsigned short*)(f + WS_WRT);
  const int t = threadIdx.x;
  const int wv = t >> 6, lane = t & 63;
  const int m = lane & 15, quad = lane >> 4;
  const size_t row0 = (size_t)blockIdx.x * 64;
  const size_t rblk0 = (size_t)blockIdx.x * 4;

  if (t < 128) {
    float s = 0.f, sq = 0.f;
    #pragma unroll
    for (int bk = 0; bk < NBKT; bk++) {
      s  += f[WS_STATS + bk * 256 + t];
      sq += f[WS_STATS + bk * 256 + 128 + t];
    }
    float mu  = s * (1.f / (float)BN_);
    float var = sq * (1.f / (float)BN_) - mu * mu;
    float rg  = rsqrtf(var + EPS_) * gamma[t];
    rsL[t] = rg;
    zbL[t] = beta[t] - mu * rg;
    wpL[t] = wp[t];
  }
  const int col = wv * 16 + m;
  bf16x8 bz[4];
  #pragma unroll
  for (int s = 0; s < 4; s++)
    bz[s] = *(const bf16x8*)(wrT + col * D_ + s * 32 + quad * 8);
  const float bias = br[col];
  const float bpv = bp[0];
  __syncthreads();

  #pragma unroll
  for (int rt = 0; rt < 4; rt++) {
    const size_t row = row0 + rt * 16 + m;      // this lane's logical H row
    float predp = 0.f;
    f32x4 acc2 = {bias, bias, bias, bias};
    #pragma unroll
    for (int s = 0; s < 4; s++) {
      const int cbase = s * 32 + quad * 8;
      bf16x8 h8 = *(const bf16x8*)(H + (((rblk0 + rt) * 4 + s) * 64 + lane) * 8);
      bf16x8 z8;
      #pragma unroll
      for (int j = 0; j < 8; j++) {
        const int c = cbase + j;
        float z = fmaf(b2f((unsigned short)h8[j]), rsL[c], zbL[c]);
        z = z > 0.f ? z : 0.f;
        predp += z * wpL[c];
        z8[j] = (short)f2b(z);
      }
      acc2 = __builtin_amdgcn_mfma_f32_16x16x32_bf16(z8, bz[s], acc2, 0, 0, 0);
    }
    predp += __shfl_xor(predp, 16); predp += __shfl_xor(predp, 32);
    if (quad == 0) out[OFF_PRED + row] = predp + bpv;
    #pragma unroll
    for (int i = 0; i < 4; i++)
      out[(row0 + rt * 16 + quad * 4 + i) * F_ + col] = acc2[i];
  }
}

extern "C" void kernel_launch(void* const* d_in, const int* in_sizes, int n_in,
                              void* d_out, int out_size, void* d_ws, size_t ws_size,
                              hipStream_t stream) {
  const float* data  = (const float*)d_in[0];
  const int*   ei    = (const int*)d_in[1];
  const float* W     = (const float*)d_in[2];
  const float* lin_w = (const float*)d_in[3];
  // d_in[4] = gnn_bias: cancels exactly through training-mode BN
  const float* gamma = (const float*)d_in[5];
  const float* beta  = (const float*)d_in[6];
  const float* Wr    = (const float*)d_in[7];
  const float* br    = (const float*)d_in[8];
  const float* wp    = (const float*)d_in[9];
  const float* bp    = (const float*)d_in[10];
  float* out = (float*)d_out;
  float* ws  = (float*)d_ws;
  unsigned short* outs = (unsigned short*)d_out;   // XT @0, A @A_U16 (scratch)

  k_prep <<<1856, 256, 0, stream>>>(data, W, lin_w, Wr, ei, ws, outs, out);
  kBC    <<<1024, 256, 0, stream>>>(outs, ws);
  kD     <<<1024, 256, 0, stream>>>(gamma, beta, br, wp, bp, ws, out);
}

// Round 15
// 122.900 us; speedup vs baseline: 1.8577x; 1.0135x over previous
//
#include <hip/hip_runtime.h>
#include <hip/hip_bf16.h>

constexpr int B_  = 128;
constexpr int N_  = 512;
constexpr int F_  = 64;
constexpr int D_  = 128;
constexpr int E_  = 8192;
constexpr int BN_ = B_ * N_;              // 65536
constexpr float SLOPE = 0.2f;
constexpr float EPS_  = 1e-5f;
constexpr int OFF_PRED = BN_ * F_;        // 4194304 (elements)
constexpr int OFF_W    = OFF_PRED + BN_;  // 4259840

// workspace float-offsets (ws = 256 MiB per the fillBuffer WRITE_SIZE)
constexpr int WS_STATS = 16896;    // f[16][256]  bucketed (sum | sumsq), 4096 floats
constexpr int NBKT     = 16;
constexpr int WS_WLT   = 25860;    // u16[128n][64k]   (bf16 Wl^T)
constexpr int WS_WRT   = 29956;    // u16[64n][128k]   (bf16 Wr^T)
constexpr int WS_Y     = 34052;    // Yf bf16, 8.4MB (byte 136208, 16B aligned)
// Yf GRANULE layout: per 16-row tile rblk (= globalrow>>4), 256 x ushort4
// granules: granule gg = f>>2 (16 of them), n = row&15:
//   Yf4[rblk*256 + gg*16 + n] = {Y[n][4f], Y[n][4f+1], Y[n][4f+2], Y[n][4f+3]}
// kBC's store: lane(m,quad) of wave wv writes gg=wv*4+quad, n=m -> the wave's
// 64 lanes write 512B CONTIGUOUS. kD's GEMM1 a-frag = 2x8B loads per K-chunk
// (gg pair {2q,2q+1} / {8+2q,8+2q+1}), 128B-segment runs.

// scratch carved out of `out` (fully overwritten later by kD's recons).
// Row strides PADDED to 544 u16 (1088 B): rows shift one 64B line each, so
// 16-row gathers spread over 16 L2 channels instead of camping on 1-2.
constexpr int XTP   = 544;
constexpr int AP    = 544;
constexpr int A_U16 = B_ * F_ * XTP;      // 4,456,448

typedef __attribute__((ext_vector_type(8))) short bf16x8;
typedef __attribute__((ext_vector_type(4))) float f32x4;

__device__ __forceinline__ float lrelu(float w) { return w > 0.f ? w : SLOPE * w; }
__device__ __forceinline__ unsigned short f2b(float v) {
  __hip_bfloat16 h = __float2bfloat16(v);
  return *(unsigned short*)&h;
}
__device__ __forceinline__ float b2f(unsigned short u) {
  __hip_bfloat16 h = *(__hip_bfloat16*)&u;
  return __bfloat162float(h);
}

// K0: fused prep, grid 1856.  (unchanged from round 14)
__global__ __launch_bounds__(256) void k_prep(
    const float* __restrict__ X, const float* __restrict__ W,
    const float* __restrict__ Wl, const float* __restrict__ Wr,
    const int* __restrict__ ei,
    float* ws, unsigned short* __restrict__ outs, float* __restrict__ out)
{
  const int t = threadIdx.x;
  const int blk = blockIdx.x;
  if (blk < 1024) {
    __shared__ unsigned short xs[64 * 66];
    const int b = blk >> 3, mseg = blk & 7;   // b in [0,128), mseg in [0,8)
    const float4* src = (const float4*)(X + ((size_t)b * N_ + mseg * 64) * F_);
    #pragma unroll
    for (int p = 0; p < 4; p++) {
      const int idx = p * 256 + t;          // [0, 1024) float4s
      float4 v = src[idx];
      const int ml = idx >> 4;              // m_local 0..63
      const int f0 = (idx & 15) << 2;       // f 0..63 step 4
      xs[(f0 + 0) * 66 + ml] = f2b(v.x);
      xs[(f0 + 1) * 66 + ml] = f2b(v.y);
      xs[(f0 + 2) * 66 + ml] = f2b(v.z);
      xs[(f0 + 3) * 66 + ml] = f2b(v.w);
    }
    __syncthreads();
    const int fr = t >> 2, j8 = t & 3;      // f-row, 16-m chunk
    const char* r = (const char*)(xs + fr * 66 + j8 * 16);  // 4B aligned
    unsigned u[8];
    #pragma unroll
    for (int c = 0; c < 8; c++) u[c] = *(const unsigned*)(r + 4 * c);
    unsigned short* dst = outs + (size_t)b * (F_ * XTP) + fr * XTP
                               + mseg * 64 + j8 * 16;        // 16B aligned
    *(uint4*)(dst)     = make_uint4(u[0], u[1], u[2], u[3]);
    *(uint4*)(dst + 8) = make_uint4(u[4], u[5], u[6], u[7]);
  } else if (blk < 1056) {
    if (blk == 1024) {
      #pragma unroll
      for (int i = 0; i < NBKT; i++) ws[WS_STATS + i * 256 + t] = 0.f;
    }
    unsigned short* wlT = (unsigned short*)(ws + WS_WLT);
    int i = (blk - 1024) * 256 + t;           // [0, 8192)
    int n = i >> 6, k = i & 63;
    wlT[i] = f2b(Wl[k * D_ + n]);
  } else if (blk < 1088) {
    unsigned short* wrT = (unsigned short*)(ws + WS_WRT);
    int i = (blk - 1056) * 256 + t;           // [0, 8192)
    int n = i >> 7, k = i & 127;
    wrT[i] = f2b(Wr[k * F_ + n]);
  } else if (blk < 1344) {
    int i = (blk - 1088) * 256 + t;           // [0, 65536)
    ((float4*)(out + OFF_W))[i] = ((const float4*)W)[i];
  } else {
    // dense masked row softmax (exact duplicate handling: cnt * e^a)
    __shared__ unsigned cnt[N_];
    __shared__ float red[8];
    unsigned short* Abf = outs + A_U16;
    const int row = blk - 1344;
    const int wv = t >> 6;
    cnt[t] = 0u; cnt[t + 256] = 0u;
    __syncthreads();
    for (int e = t; e < E_; e += 256) {
      int d = ei[E_ + e];
      if (d == row) atomicAdd(&cnt[ei[e]], 1u);
    }
    __syncthreads();
    const int s0 = t, s1 = t + 256;
    const float a0 = lrelu(W[row * N_ + s0]);
    const float a1 = lrelu(W[row * N_ + s1]);
    const unsigned c0 = cnt[s0] + (s0 == row ? 1u : 0u);
    const unsigned c1 = cnt[s1] + (s1 == row ? 1u : 0u);
    float m = fmaxf(c0 ? a0 : -3.4e38f, c1 ? a1 : -3.4e38f);
    #pragma unroll
    for (int off = 32; off; off >>= 1) m = fmaxf(m, __shfl_xor(m, off));
    if ((t & 63) == 0) red[wv] = m;
    __syncthreads();
    const float amax = fmaxf(fmaxf(red[0], red[1]), fmaxf(red[2], red[3]));
    const float e0 = c0 ? (float)c0 * __expf(a0 - amax) : 0.f;
    const float e1 = c1 ? (float)c1 * __expf(a1 - amax) : 0.f;
    float sm = e0 + e1;
    #pragma unroll
    for (int off = 32; off; off >>= 1) sm += __shfl_xor(sm, off);
    if ((t & 63) == 0) red[4 + wv] = sm;
    __syncthreads();
    const float inv = 1.f / (red[4] + red[5] + red[6] + red[7]);
    Abf[row * AP + s0] = f2b(e0 * inv);
    Abf[row * AP + s1] = f2b(e1 * inv);
  }
}

// K1: aggregation + BN stats; writes Yf (8.4MB granule layout) instead of Hf.
//   Y-GEMM (A LDS-staged, prefetch pipeline) -> Yf coalesced 8B stores + ys
//   h-GEMM from ys -> STATS ONLY (h discarded; kD recomputes it from Yf)
// grid = 1024: b = blk&127 (blocks sharing XT_b sit stride-128 => same XCD).
__global__ __launch_bounds__(256, 4) void kBC(
    const unsigned short* __restrict__ XT, float* ws)
{
  __shared__ __align__(16) unsigned short As[64 * 128];   // A K-chunk, swizzled
  __shared__ __align__(16) unsigned short ys[64 * 64];    // Y tile, XOR-swizzled
  float* f = ws;
  ushort4* Yf4 = (ushort4*)(ws + WS_Y);
  const unsigned short* wlT = (const unsigned short*)(ws + WS_WLT);
  const unsigned short* Abf = XT + A_U16;
  const int t = threadIdx.x;
  const int wv = t >> 6, lane = t & 63;
  const int m = lane & 15, quad = lane >> 4;
  const int b = blockIdx.x & 127, ns = blockIdx.x >> 7;   // ns in [0,8)
  const int n0 = ns * 64;

  // ---- Y GEMM: Y^T[f][n] = XT_b[f][:] . A[n][:]; wave wv = f-rows [16wv,16wv+16) ----
  const unsigned short* af = XT + (size_t)b * (F_ * XTP) + (wv * 16 + m) * XTP;
  const int srow = wv * 4 + (lane >> 4);    // stage: 4 rows/wave (+16p)
  const int sg   = lane & 15;               // 16B granule within 256B chunk
  f32x4 acc[4] = {{0.f,0.f,0.f,0.f},{0.f,0.f,0.f,0.f},
                  {0.f,0.f,0.f,0.f},{0.f,0.f,0.f,0.f}};
  bf16x8 vreg[4], areg[4], aregN[4];
  #pragma unroll
  for (int p = 0; p < 4; p++) {
    const int rr = srow + 16 * p;
    vreg[p] = *(const bf16x8*)(Abf + (n0 + rr) * AP + sg * 8);
  }
  #pragma unroll
  for (int kk = 0; kk < 4; kk++)
    areg[kk] = *(const bf16x8*)(af + kk * 32 + quad * 8);

  for (int kc = 0; kc < 4; kc++) {
    #pragma unroll
    for (int p = 0; p < 4; p++) {
      const int rr = srow + 16 * p;
      *(bf16x8*)(As + rr * 128 + ((sg ^ (rr & 7)) << 3)) = vreg[p];
    }
    __syncthreads();
    if (kc < 3) {
      #pragma unroll
      for (int p = 0; p < 4; p++) {
        const int rr = srow + 16 * p;
        vreg[p] = *(const bf16x8*)(Abf + (n0 + rr) * AP + (kc + 1) * 128 + sg * 8);
      }
      #pragma unroll
      for (int kk = 0; kk < 4; kk++)
        aregN[kk] = *(const bf16x8*)(af + (kc + 1) * 128 + kk * 32 + quad * 8);
    }
    #pragma unroll
    for (int kk = 0; kk < 4; kk++) {
      bf16x8 a = areg[kk];
      #pragma unroll
      for (int nt = 0; nt < 4; nt++) {
        const int n2 = nt * 16 + m;
        bf16x8 bb = *(const bf16x8*)(As + n2 * 128 +
                                     ((((kk << 2) + quad) ^ (n2 & 7)) << 3));
        acc[nt] = __builtin_amdgcn_mfma_f32_16x16x32_bf16(a, bb, acc[nt], 0, 0, 0);
      }
    }
    __syncthreads();
    #pragma unroll
    for (int kk = 0; kk < 4; kk++) areg[kk] = aregN[kk];
  }
  // Y tile -> Yf global (coalesced: wave writes 512B run) + swizzled ys
  #pragma unroll
  for (int nt = 0; nt < 4; nt++) {
    ushort4 y4;
    y4.x = f2b(acc[nt][0]); y4.y = f2b(acc[nt][1]);
    y4.z = f2b(acc[nt][2]); y4.w = f2b(acc[nt][3]);
    const int rblk = (b * 32 + ns * 4 + nt);
    Yf4[(size_t)rblk * 256 + wv * 64 + lane] = y4;   // gg=wv*4+quad, n=m
    const int n = nt * 16 + m;
    const int c = (wv * 16 + quad * 4) ^ ((n & 7) << 3);
    *(ushort4*)(ys + n * 64 + c) = y4;
  }
  __syncthreads();

  // ---- h GEMM from ys (STATS ONLY): wave wv owns d0 = wv*32 ----
  const int d0 = wv * 32;
  bf16x8 bw00 = *(const bf16x8*)(wlT + (d0 + m) * 64 + quad * 8);
  bf16x8 bw01 = *(const bf16x8*)(wlT + (d0 + m) * 64 + 32 + quad * 8);
  bf16x8 bw10 = *(const bf16x8*)(wlT + (d0 + 16 + m) * 64 + quad * 8);
  bf16x8 bw11 = *(const bf16x8*)(wlT + (d0 + 16 + m) * 64 + 32 + quad * 8);
  f32x4 acch[4][2];
  #pragma unroll
  for (int nt = 0; nt < 4; nt++) {
    acch[nt][0] = f32x4{0.f,0.f,0.f,0.f};
    acch[nt][1] = f32x4{0.f,0.f,0.f,0.f};
  }
  #pragma unroll
  for (int nt = 0; nt < 4; nt++) {
    const int n2 = nt * 16 + m;
    const int sw = (n2 & 7) << 3;
    bf16x8 aA = *(const bf16x8*)(ys + n2 * 64 + ((quad * 8) ^ sw));
    bf16x8 aB = *(const bf16x8*)(ys + n2 * 64 + ((32 + quad * 8) ^ sw));
    acch[nt][0] = __builtin_amdgcn_mfma_f32_16x16x32_bf16(aA, bw00, acch[nt][0], 0, 0, 0);
    acch[nt][0] = __builtin_amdgcn_mfma_f32_16x16x32_bf16(aB, bw01, acch[nt][0], 0, 0, 0);
    acch[nt][1] = __builtin_amdgcn_mfma_f32_16x16x32_bf16(aA, bw10, acch[nt][1], 0, 0, 0);
    acch[nt][1] = __builtin_amdgcn_mfma_f32_16x16x32_bf16(aB, bw11, acch[nt][1], 0, 0, 0);
  }

  // ---- stat accumulation -> shuffle reduce -> bucketed atomics ----
  float sm0 = 0.f, sq0 = 0.f, sm1 = 0.f, sq1 = 0.f;
  #pragma unroll
  for (int nt = 0; nt < 4; nt++) {
    #pragma unroll
    for (int i = 0; i < 4; i++) {
      float v0 = acch[nt][0][i], v1 = acch[nt][1][i];
      sm0 += v0; sq0 += v0 * v0;
      sm1 += v1; sq1 += v1 * v1;
    }
  }
  sm0 += __shfl_xor(sm0, 16); sm0 += __shfl_xor(sm0, 32);
  sq0 += __shfl_xor(sq0, 16); sq0 += __shfl_xor(sq0, 32);
  sm1 += __shfl_xor(sm1, 16); sm1 += __shfl_xor(sm1, 32);
  sq1 += __shfl_xor(sq1, 16); sq1 += __shfl_xor(sq1, 32);
  if (quad == 0) {
    float* st = f + WS_STATS + (blockIdx.x & (NBKT - 1)) * 256;
    atomicAdd(&st[d0 + m], sm0);
    atomicAdd(&st[128 + d0 + m], sq0);
    atomicAdd(&st[d0 + 16 + m], sm1);
    atomicAdd(&st[128 + d0 + 16 + m], sq1);
  }
}

// K2: epilogue: read Yf, GEMM1 (h = Y@Wl), BN+ReLU -> zs -> GEMM2 + pred.
// Phase-2 mapping identical to round-11 kMega (correctness-verified there).
// grid 1024 (4 blocks/CU), 64 rows/block.
__global__ __launch_bounds__(256, 4) void kD(
    const float* __restrict__ gamma, const float* __restrict__ beta,
    const float* __restrict__ br, const float* __restrict__ wp,
    const float* __restrict__ bp, float* ws, float* __restrict__ out)
{
  constexpr int LDP = 136;                        // zs row pad
  __shared__ __align__(16) unsigned short zs[64 * LDP];
  __shared__ float rsL[D_], zbL[D_], wpL[D_];
  float* f = ws;
  const ushort4* Yf4 = (const ushort4*)(f + WS_Y);
  const unsigned short* wlT = (const unsigned short*)(f + WS_WLT);
  const unsigned short* wrT = (const unsigned short*)(f + WS_WRT);
  const int t = threadIdx.x;
  const int wv = t >> 6, lane = t & 63;
  const int m = lane & 15, quad = lane >> 4;
  const size_t row0 = (size_t)blockIdx.x * 64;
  const size_t rblk0 = (size_t)blockIdx.x * 4;

  if (t < 128) {
    float s = 0.f, sq = 0.f;
    #pragma unroll
    for (int bk = 0; bk < NBKT; bk++) {
      s  += f[WS_STATS + bk * 256 + t];
      sq += f[WS_STATS + bk * 256 + 128 + t];
    }
    float mu  = s * (1.f / (float)BN_);
    float var = sq * (1.f / (float)BN_) - mu * mu;
    float rg  = rsqrtf(var + EPS_) * gamma[t];
    rsL[t] = rg;
    zbL[t] = beta[t] - mu * rg;
    wpL[t] = wp[t];
  }
  // GEMM1 B-frags (col-tiles T0=2wv, T1=2wv+1) + GEMM2 B-frags, loaded once
  const int d0 = wv * 32;
  bf16x8 bw00 = *(const bf16x8*)(wlT + (d0 + m) * 64 + quad * 8);
  bf16x8 bw01 = *(const bf16x8*)(wlT + (d0 + m) * 64 + 32 + quad * 8);
  bf16x8 bw10 = *(const bf16x8*)(wlT + (d0 + 16 + m) * 64 + quad * 8);
  bf16x8 bw11 = *(const bf16x8*)(wlT + (d0 + 16 + m) * 64 + 32 + quad * 8);
  const int col = wv * 16 + m;
  bf16x8 bz[4];
  #pragma unroll
  for (int s = 0; s < 4; s++)
    bz[s] = *(const bf16x8*)(wrT + col * D_ + s * 32 + quad * 8);
  const float bias = br[col];
  const float bpv = bp[0];
  __syncthreads();   // rsL/zbL ready

  // ---- GEMM1 + BN + ReLU -> zs, per 16-row tile rt ----
  #pragma unroll
  for (int rt = 0; rt < 4; rt++) {
    const size_t base = (rblk0 + rt) * 256;
    // a-frags: Y[n=m][f]: chunk0 f=quad*8 (gg 2q,2q+1), chunk1 f=32+quad*8
    bf16x8 a0, a1;
    ((ushort4*)&a0)[0] = Yf4[base + (2 * quad) * 16 + m];
    ((ushort4*)&a0)[1] = Yf4[base + (2 * quad + 1) * 16 + m];
    ((ushort4*)&a1)[0] = Yf4[base + (8 + 2 * quad) * 16 + m];
    ((ushort4*)&a1)[1] = Yf4[base + (8 + 2 * quad + 1) * 16 + m];
    f32x4 acc0 = {0.f, 0.f, 0.f, 0.f}, acc1 = {0.f, 0.f, 0.f, 0.f};
    acc0 = __builtin_amdgcn_mfma_f32_16x16x32_bf16(a0, bw00, acc0, 0, 0, 0);
    acc0 = __builtin_amdgcn_mfma_f32_16x16x32_bf16(a1, bw01, acc0, 0, 0, 0);
    acc1 = __builtin_amdgcn_mfma_f32_16x16x32_bf16(a0, bw10, acc1, 0, 0, 0);
    acc1 = __builtin_amdgcn_mfma_f32_16x16x32_bf16(a1, bw11, acc1, 0, 0, 0);
    // BN + ReLU -> zs (h rows quad*4+i, cols d0+m / d0+16+m)
    const int c0 = d0 + m, c1 = d0 + 16 + m;
    const float rs0 = rsL[c0], be0 = zbL[c0];
    const float rs1 = rsL[c1], be1 = zbL[c1];
    #pragma unroll
    for (int i = 0; i < 4; i++) {
      const int row = rt * 16 + quad * 4 + i;
      float z0 = fmaf(acc0[i], rs0, be0);
      float z1 = fmaf(acc1[i], rs1, be1);
      zs[row * LDP + c0] = f2b(z0 > 0.f ? z0 : 0.f);
      zs[row * LDP + c1] = f2b(z1 > 0.f ? z1 : 0.f);
    }
  }
  __syncthreads();

  // ---- GEMM2: recons, wave wv -> col-tile wv; 4 row-tiles ----
  #pragma unroll
  for (int rt = 0; rt < 4; rt++) {
    f32x4 acc2 = {bias, bias, bias, bias};
    #pragma unroll
    for (int s = 0; s < 4; s++) {
      bf16x8 az = *(const bf16x8*)(zs + (rt * 16 + m) * LDP + s * 32 + quad * 8);
      acc2 = __builtin_amdgcn_mfma_f32_16x16x32_bf16(az, bz[s], acc2, 0, 0, 0);
    }
    #pragma unroll
    for (int i = 0; i < 4; i++)
      out[(row0 + rt * 16 + quad * 4 + i) * F_ + col] = acc2[i];
  }

  // ---- pred head: 4 lanes per row, 32 d each ----
  {
    const int r = t >> 2, j = t & 3;
    float a = 0.f;
    #pragma unroll
    for (int k = 0; k < 32; k++) {
      const int d = j * 32 + k;
      a += b2f(zs[r * LDP + d]) * wpL[d];
    }
    a += __shfl_xor(a, 1); a += __shfl_xor(a, 2);
    if (j == 0) out[OFF_PRED + row0 + r] = a + bpv;
  }
}

extern "C" void kernel_launch(void* const* d_in, const int* in_sizes, int n_in,
                              void* d_out, int out_size, void* d_ws, size_t ws_size,
                              hipStream_t stream) {
  const float* data  = (const float*)d_in[0];
  const int*   ei    = (const int*)d_in[1];
  const float* W     = (const float*)d_in[2];
  const float* lin_w = (const float*)d_in[3];
  // d_in[4] = gnn_bias: cancels exactly through training-mode BN
  const float* gamma = (const float*)d_in[5];
  const float* beta  = (const float*)d_in[6];
  const float* Wr    = (const float*)d_in[7];
  const float* br    = (const float*)d_in[8];
  const float* wp    = (const float*)d_in[9];
  const float* bp    = (const float*)d_in[10];
  float* out = (float*)d_out;
  float* ws  = (float*)d_ws;
  unsigned short* outs = (unsigned short*)d_out;   // XT @0, A @A_U16 (scratch)

  k_prep <<<1856, 256, 0, stream>>>(data, W, lin_w, Wr, ei, ws, outs, out);
  kBC    <<<1024, 256, 0, stream>>>(outs, ws);
  kD     <<<1024, 256, 0, stream>>>(gamma, beta, br, wp, bp, ws, out);
}